// Round 15
// baseline (880.499 us; speedup 1.0000x reference)
//
#include <hip/hip_runtime.h>
#include <hip/hip_bf16.h>
#include <math.h>

#define B_  128
#define S_  512
#define H_  768
#define NH_ 8
#define T_  20
#define HD_ 96

typedef unsigned short u16;
typedef unsigned int   u32;

typedef __attribute__((ext_vector_type(8))) short bhalf8;
typedef __attribute__((ext_vector_type(4))) float f32x4;

union U8 { bhalf8 s; u32 u[4]; };

__device__ __forceinline__ f32x4 mfma16(bhalf8 a, bhalf8 b, f32x4 c){
  return __builtin_amdgcn_mfma_f32_16x16x32_bf16(a, b, c, 0, 0, 0);
}
__device__ __forceinline__ u32 cvtpk(float lo, float hi){
  u32 r; asm volatile("v_cvt_pk_bf16_f32 %0, %1, %2" : "=v"(r) : "v"(lo), "v"(hi));
  return r;
}
__device__ __forceinline__ float wsum(float v){
  #pragma unroll
  for(int o=32;o;o>>=1) v += __shfl_xor(v,o);
  return v;
}
__device__ __forceinline__ u16 f2bf(float f){
  u32 u = __float_as_uint(f);
  u32 r = (u + 0x7fffu + ((u>>16)&1u)) >> 16;
  return (u16)r;
}
__device__ __forceinline__ float bf2f(u32 bits){
  return __uint_as_float(bits<<16);
}

// ------ ALL weight conversions in ONE launch (dst buffers contiguous in ws) ------
__global__ void k_cvtall(const float* __restrict__ s0, const float* __restrict__ s1,
                         const float* __restrict__ s2, const float* __restrict__ s3,
                         const float* __restrict__ s4, const float* __restrict__ s5,
                         const float* __restrict__ s6, const float* __restrict__ s7,
                         const float* __restrict__ s8, const float* __restrict__ s9,
                         const float* __restrict__ s10, const float* __restrict__ s11,
                         u16* __restrict__ dst){
  const int NP = (H_*H_)/2;
  int idx = blockIdx.x*256 + threadIdx.x;
  int seg, po;
  if(idx < 11*NP){ seg = idx / NP; po = idx - seg*NP; }
  else           { seg = 11; po = idx - 11*NP; if(po >= NP/2) return; }
  const float* src =
    seg==0? s0 : seg==1? s1 : seg==2? s2 : seg==3? s3 : seg==4? s4 : seg==5? s5 :
    seg==6? s6 : seg==7? s7 : seg==8? s8 : seg==9? s9 : seg==10? s10 : s11;
  u32 r = cvtpk(src[2*po], src[2*po+1]);
  *(u32*)(dst + (size_t)seg*(H_*H_) + 2*po) = r;
}

// ------- ehs -> ehs_b + ehsT (bf16), 64x64 tiles; ALSO masked pool partials -------
__global__ __launch_bounds__(256) void k_prep(const float* __restrict__ ehs,
                                              const int* __restrict__ sm,
                                              const int* __restrict__ im,
                                              u16* __restrict__ ehs_b,
                                              u16* __restrict__ ehsT,
                                              float* __restrict__ pool_part){
  int blk = blockIdx.x;
  int b  = blk / 96;
  int r  = blk % 96;
  int sb = r / 12, hb = r % 12;
  int s0 = sb*64, h0 = hb*64;
  __shared__ float tile[64][65];
  __shared__ float marr[2][64];
  __shared__ float red[2][4][64];
  int t = threadIdx.x;
  if(t < 64)       marr[0][t]    = (float)sm[b*S_ + s0 + t];
  else if(t < 128) marr[1][t-64] = (float)im[b*S_ + s0 + (t-64)];
  const float* src = ehs + ((size_t)b*S_ + s0)*H_ + h0;
  #pragma unroll
  for(int p2=0;p2<4;p2++){
    int row = p2*16 + (t>>4);
    int c4  = (t&15)*4;
    float4 v = *(const float4*)(src + (size_t)row*H_ + c4);
    tile[row][c4+0]=v.x; tile[row][c4+1]=v.y; tile[row][c4+2]=v.z; tile[row][c4+3]=v.w;
    u32 lo = cvtpk(v.x, v.y), hi2 = cvtpk(v.z, v.w);
    u32* dst = (u32*)(ehs_b + ((size_t)b*S_ + s0 + row)*H_ + h0 + c4);
    dst[0]=lo; dst[1]=hi2;
  }
  __syncthreads();
  #pragma unroll
  for(int p2=0;p2<4;p2++){
    int hr = p2*16 + (t>>4);
    int sg2 = (t&15)*4;
    float a0 = tile[sg2+0][hr], a1 = tile[sg2+1][hr];
    float a2 = tile[sg2+2][hr], a3 = tile[sg2+3][hr];
    u32 lo = cvtpk(a0,a1), hi2 = cvtpk(a2,a3);
    u32* dst = (u32*)(ehsT + ((size_t)b*H_ + h0 + hr)*S_ + s0 + sg2);
    dst[0]=lo; dst[1]=hi2;
  }
  int h = t & 63, sg = t >> 6;
  float ts=0.f, is=0.f;
  #pragma unroll
  for(int k=0;k<16;k++){
    float v = tile[sg*16+k][h];
    ts += v*marr[0][sg*16+k];
    is += v*marr[1][sg*16+k];
  }
  red[0][sg][h]=ts; red[1][sg][h]=is;
  __syncthreads();
  if(sg==0){
    float tsum = red[0][0][h]+red[0][1][h]+red[0][2][h]+red[0][3][h];
    float isum = red[1][0][h]+red[1][1][h]+red[1][2][h]+red[1][3][h];
    pool_part[(((size_t)0*B_+b)*8+sb)*H_ + h0 + h] = tsum;
    pool_part[(((size_t)1*B_+b)*8+sb)*H_ + h0 + h] = isum;
  }
}

// ------ finalize pooling ------
__global__ __launch_bounds__(256) void k_poolfin(const float* __restrict__ pool_part,
                                                 const int* __restrict__ sm,
                                                 const int* __restrict__ im,
                                                 u16* __restrict__ pt_b,
                                                 u16* __restrict__ pi_b){
  int b = blockIdx.x, tid = threadIdx.x, lane = tid&63, w = tid>>6;
  __shared__ float red2[2][4];
  float tl=0.f, il=0.f;
  for(int s=tid; s<S_; s+=256){ tl += (float)sm[b*S_+s]; il += (float)im[b*S_+s]; }
  tl = wsum(tl); il = wsum(il);
  if(lane==0){ red2[0][w]=tl; red2[1][w]=il; }
  __syncthreads();
  float tlen = fmaxf(red2[0][0]+red2[0][1]+red2[0][2]+red2[0][3], 1e-9f);
  float ilen = fmaxf(red2[1][0]+red2[1][1]+red2[1][2]+red2[1][3], 1e-9f);
  for(int h=tid; h<H_; h+=256){
    float ts=0.f, is2=0.f;
    #pragma unroll
    for(int sb=0; sb<8; sb++){
      ts  += pool_part[(((size_t)0*B_+b)*8+sb)*H_ + h];
      is2 += pool_part[(((size_t)1*B_+b)*8+sb)*H_ + h];
    }
    pt_b[b*H_+h] = f2bf(ts/tlen);
    pi_b[b*H_+h] = f2bf(is2/ilen);
  }
}

// ---------------- WkT[mha][n][k] = Wk[k][n] (bf16) ----------------
__global__ void k_wkt(const float* __restrict__ taWin, const float* __restrict__ iaWin,
                      u16* __restrict__ WkT){
  int blk = blockIdx.x; int mha = blk/576; int t = blk%576;
  const float* Wk = (mha? iaWin : taWin) + (size_t)H_*H_;
  int bx = t%24, by = t/24;
  __shared__ float tile[32][33];
  int tx = threadIdx.x & 31, ty = threadIdx.x >> 5;
  for(int rr=ty; rr<32; rr+=8) tile[rr][tx] = Wk[(size_t)(by*32+rr)*H_ + bx*32+tx];
  __syncthreads();
  u16* dst = WkT + (size_t)mha*H_*H_;
  for(int rr=ty; rr<32; rr+=8) dst[(size_t)(bx*32+rr)*H_ + by*32+tx] = f2bf(tile[tx][rr]);
}

// ------ fused seed proj BOTH modalities ------
__global__ __launch_bounds__(512) void k_seed2(const u16* __restrict__ pt_b,
                                               const u16* __restrict__ pi_b,
                                               const u16* __restrict__ tW1_b, const float* __restrict__ tb1,
                                               const float* __restrict__ tg,  const float* __restrict__ tbe,
                                               const u16* __restrict__ tW2_b, const float* __restrict__ tb2,
                                               const u16* __restrict__ iW1_b, const float* __restrict__ ib1,
                                               const float* __restrict__ ig,  const float* __restrict__ ibe,
                                               const u16* __restrict__ iW2_b, const float* __restrict__ ib2,
                                               float* __restrict__ st, float* __restrict__ si){
  int which = blockIdx.x >= (B_/16);
  int row0 = (blockIdx.x - which*(B_/16))*16;
  const u16* x_b  = which? pi_b  : pt_b;
  const u16* W1_b = which? iW1_b : tW1_b;
  const float* b1 = which? ib1 : tb1;
  const float* g  = which? ig  : tg;
  const float* be = which? ibe : tbe;
  const u16* W2_b = which? iW2_b : tW2_b;
  const float* b2 = which? ib2 : tb2;
  float* out      = which? si : st;
  int tid = threadIdx.x, lane = tid&63, w = tid>>6;
  __shared__ u16 ln[16][772];
  f32x4 acc[6];
  #pragma unroll
  for(int j=0;j<6;j++) acc[j] = (f32x4){0.f,0.f,0.f,0.f};
  for(int kt=0;kt<24;kt++){
    int ko = kt*32 + (lane>>4)*8;
    bhalf8 a = *(const bhalf8*)(x_b + (size_t)(row0 + (lane&15))*H_ + ko);
    bhalf8 bb[6];
    #pragma unroll
    for(int j=0;j<6;j++){
      int row = (w*6+j)*16 + (lane&15);
      bb[j] = *(const bhalf8*)(W1_b + (size_t)row*H_ + ko);
    }
    #pragma unroll
    for(int j=0;j<6;j++) acc[j] = mfma16(a, bb[j], acc[j]);
  }
  #pragma unroll
  for(int j=0;j<6;j++){
    int c = (w*6+j)*16 + (lane&15);
    float bv = b1[c];
    #pragma unroll
    for(int rr=0;rr<4;rr++){
      int r = (lane>>4)*4 + rr;
      float v = acc[j][rr] + bv;
      ln[r][c] = f2bf((v>=0.f)? v : 0.01f*v);
    }
  }
  __syncthreads();
  for(int ri=0; ri<2; ri++){
    int r = w*2 + ri;
    float v[12]; float s = 0.f;
    #pragma unroll
    for(int i=0;i<12;i++){ v[i] = bf2f(ln[r][lane + 64*i]); s += v[i]; }
    s = wsum(s);
    float mean = s/(float)H_;
    float pv = 0.f;
    #pragma unroll
    for(int i=0;i<12;i++){ float d = v[i]-mean; pv += d*d; }
    pv = wsum(pv);
    float rstd = rsqrtf(pv/(float)H_ + 1e-5f);
    #pragma unroll
    for(int i=0;i<12;i++){
      int c = lane + 64*i;
      ln[r][c] = f2bf((v[i]-mean)*rstd*g[c] + be[c]);
    }
  }
  __syncthreads();
  f32x4 o[6];
  #pragma unroll
  for(int j=0;j<6;j++) o[j] = (f32x4){0.f,0.f,0.f,0.f};
  for(int kt=0;kt<24;kt++){
    int ko = kt*32 + (lane>>4)*8;
    bhalf8 a = *(const bhalf8*)(&ln[lane&15][ko]);
    bhalf8 bb[6];
    #pragma unroll
    for(int j=0;j<6;j++){
      int row = (w*6+j)*16 + (lane&15);
      bb[j] = *(const bhalf8*)(W2_b + (size_t)row*H_ + ko);
    }
    #pragma unroll
    for(int j=0;j<6;j++) o[j] = mfma16(a, bb[j], o[j]);
  }
  #pragma unroll
  for(int j=0;j<6;j++){
    int c = (w*6+j)*16 + (lane&15);
    float bv = b2[c];
    #pragma unroll
    for(int rr=0;rr<4;rr++){
      int r = (lane>>4)*4 + rr;
      out[(size_t)(row0 + r)*H_ + c] = o[j][rr] + bv;
    }
  }
}

// ---------------- query (padded to 32 rows, bf16) ----------------
__global__ void k_query(const float* __restrict__ st, const float* __restrict__ si,
                        const float* __restrict__ rel, u16* __restrict__ query_b){
  int b = blockIdx.x; int tid = threadIdx.x;
  float a = rel[b];
  const float c = 9.210340371976184f/(float)H_;
  for(int t=0;t<32;t++){
    for(int h=tid;h<H_;h+=256){
      float val = 0.f;
      if(t < T_){
        float ang = (float)t * __expf(-(float)(h & ~1) * c);
        float pe  = (h&1)? __cosf(ang) : __sinf(ang);
        val = a*si[b*H_+h] + (1.f-a)*st[b*H_+h] + pe;
      }
      query_b[(size_t)b*32*H_ + t*H_ + h] = f2bf(val);
    }
  }
}

// ---- FUSED qh+U: qh = query@Wq^T+bq (LDS only), then U = qh_h@Wk_h + bias ----
__global__ __launch_bounds__(512) void k_qu(const u16* __restrict__ query_b,
                                            const u16* __restrict__ Wq_b,
                                            const u16* __restrict__ WkT,
                                            const float* __restrict__ taBin,
                                            const float* __restrict__ iaBin,
                                            u16* __restrict__ U_b,
                                            float* __restrict__ bias_ws){
  int gb = blockIdx.x; int b = gb>>1, mha = gb&1;
  int tid = threadIdx.x, lane = tid&63, w = tid>>6;
  const u16* Q  = query_b + (size_t)b*32*H_;
  const u16* Wq = Wq_b + (size_t)mha*H_*H_;
  const u16* Wk = WkT + (size_t)mha*H_*H_;
  const float* bIn = mha? iaBin : taBin;
  u16* Up = U_b + (size_t)gb*160*H_;
  __shared__ u16 qh_s[32][776];
  __shared__ u16 ut[20][776];
  const float rscale = 0.10206207261596577f;

  {
    f32x4 acc[2][6];
    #pragma unroll
    for(int i=0;i<2;i++)
      #pragma unroll
      for(int j=0;j<6;j++) acc[i][j] = (f32x4){0.f,0.f,0.f,0.f};
    for(int kt=0;kt<24;kt++){
      int ko = kt*32 + (lane>>4)*8;
      bhalf8 a[2];
      #pragma unroll
      for(int mt=0;mt<2;mt++)
        a[mt] = *(const bhalf8*)(Q + (size_t)(mt*16 + (lane&15))*H_ + ko);
      bhalf8 bb[6];
      #pragma unroll
      for(int j=0;j<6;j++){
        int row = (w*6+j)*16 + (lane&15);
        bb[j] = *(const bhalf8*)(Wq + (size_t)row*H_ + ko);
      }
      #pragma unroll
      for(int mt=0;mt<2;mt++)
        #pragma unroll
        for(int j=0;j<6;j++) acc[mt][j] = mfma16(a[mt], bb[j], acc[mt][j]);
    }
    #pragma unroll
    for(int mt=0;mt<2;mt++)
      #pragma unroll
      for(int j=0;j<6;j++){
        int col = (w*6+j)*16 + (lane&15);
        float bq = bIn[col];
        #pragma unroll
        for(int rr=0;rr<4;rr++){
          int row = mt*16 + (lane>>4)*4 + rr;
          qh_s[row][col] = f2bf(acc[mt][j][rr] + bq);
        }
      }
  }
  __syncthreads();

  for(int h=0; h<8; h++){
    int hd0 = h*HD_;
    for(int jn=0; jn<6; jn++){
      int nb = (w*6+jn)*16 + (lane&15);
      bhalf8 bb[3];
      #pragma unroll
      for(int kt=0;kt<3;kt++)
        bb[kt] = *(const bhalf8*)(Wk + (size_t)nb*H_ + hd0 + kt*32 + (lane>>4)*8);
      #pragma unroll
      for(int mt=0; mt<2; mt++){
        bhalf8 a[3];
        #pragma unroll
        for(int kt=0;kt<3;kt++){
          int trow = mt*16 + (lane&15);
          a[kt] = *(const bhalf8*)(&qh_s[trow][hd0 + kt*32 + (lane>>4)*8]);
        }
        f32x4 acc = (f32x4){0.f,0.f,0.f,0.f};
        #pragma unroll
        for(int kt=0;kt<3;kt++) acc = mfma16(a[kt], bb[kt], acc);
        #pragma unroll
        for(int rr=0;rr<4;rr++){
          int trow = mt*16 + (lane>>4)*4 + rr;
          if(trow < T_)
            ut[trow][nb] = f2bf(acc[rr]*rscale);
        }
      }
    }
    __syncthreads();
    for(int e=tid; e<20*384; e+=512){
      int r = e/384, c2 = (e%384)*2;
      u32 v = *(const u32*)&ut[r][c2];
      *(u32*)(Up + (size_t)(h*T_ + r)*H_ + c2) = v;
    }
    __syncthreads();
  }
  if(tid < 160){
    int h = tid/T_, t = tid%T_; int hd0 = h*HD_;
    float p = 0.f;
    for(int d=0; d<HD_; d++)
      p += bf2f(qh_s[t][hd0 + d]) * bIn[H_ + hd0 + d];
    bias_ws[gb*160 + tid] = p*rscale;
  }
}

// ---- scores + single-pass softmax -> P; 2-stage software-pipelined K-loop (R15) ----
__global__ __launch_bounds__(512,4) void k_scores2(const u16* __restrict__ ehs_b,
                                                   const u16* __restrict__ U_b,
                                                   const float* __restrict__ bias_ws,
                                                   const int* __restrict__ smask,
                                                   const int* __restrict__ imask,
                                                   u16* __restrict__ P_b){
  int g = blockIdx.x;
  int x = g & 7, sl = g >> 3;
  int b = x*16 + (sl>>2);
  int var = sl & 3; int mha = var>>1, rhalf = var&1;
  int gb = 2*b + mha;
  const int* msk = mha? imask : smask;
  int tid = threadIdx.x, lane = tid&63, w = tid>>6;
  int rbase = rhalf*80;
  __shared__ float sbias[80];
  __shared__ float pmax[80][8];
  __shared__ float psum[80][8];
  __shared__ float mfin[80], sinv[80];
  __shared__ u16 pst[16][520];
  if(tid < 80) sbias[tid] = bias_ws[gb*160 + rbase + tid];
  __syncthreads();
  const u16* Ub = U_b + (size_t)gb*160*H_;
  const u16* Eb = ehs_b + (size_t)b*S_*H_;
  bool mk[4];
  #pragma unroll
  for(int j=0;j<4;j++) mk[j] = msk[b*S_ + w*64 + j*16 + (lane&15)] != 0;

  f32x4 acc[5][4];
  #pragma unroll
  for(int i=0;i<5;i++)
    #pragma unroll
    for(int j=0;j<4;j++) acc[i][j] = (f32x4){0.f,0.f,0.f,0.f};

  // 2-stage pipeline: fragments of iteration k+1 issued before MFMAs of k
  bhalf8 aA[5], bA[4], aB[5], bB[4];
  {
    int ko = (lane>>4)*8;
    #pragma unroll
    for(int i=0;i<5;i++) aA[i] = *(const bhalf8*)(Ub + (size_t)(rbase + i*16 + (lane&15))*H_ + ko);
    #pragma unroll
    for(int j=0;j<4;j++) bA[j] = *(const bhalf8*)(Eb + (size_t)(w*64 + j*16 + (lane&15))*H_ + ko);
  }
  for(int kt=0; kt<24; kt+=2){
    {
      int ko = (kt+1)*32 + (lane>>4)*8;
      #pragma unroll
      for(int i=0;i<5;i++) aB[i] = *(const bhalf8*)(Ub + (size_t)(rbase + i*16 + (lane&15))*H_ + ko);
      #pragma unroll
      for(int j=0;j<4;j++) bB[j] = *(const bhalf8*)(Eb + (size_t)(w*64 + j*16 + (lane&15))*H_ + ko);
    }
    #pragma unroll
    for(int i=0;i<5;i++)
      #pragma unroll
      for(int j=0;j<4;j++) acc[i][j] = mfma16(aA[i], bA[j], acc[i][j]);
    if(kt+2 < 24){
      int ko = (kt+2)*32 + (lane>>4)*8;
      #pragma unroll
      for(int i=0;i<5;i++) aA[i] = *(const bhalf8*)(Ub + (size_t)(rbase + i*16 + (lane&15))*H_ + ko);
      #pragma unroll
      for(int j=0;j<4;j++) bA[j] = *(const bhalf8*)(Eb + (size_t)(w*64 + j*16 + (lane&15))*H_ + ko);
    }
    #pragma unroll
    for(int i=0;i<5;i++)
      #pragma unroll
      for(int j=0;j<4;j++) acc[i][j] = mfma16(aB[i], bB[j], acc[i][j]);
  }

  #pragma unroll
  for(int i=0;i<5;i++)
    #pragma unroll
    for(int rr=0;rr<4;rr++){
      int row = i*16 + (lane>>4)*4 + rr;
      float bias = sbias[row];
      float vmax = -3e38f;
      #pragma unroll
      for(int j=0;j<4;j++){
        float v = acc[i][j][rr] + bias;
        acc[i][j][rr] = v;
        if(mk[j]) vmax = fmaxf(vmax, v);
      }
      #pragma unroll
      for(int o=1;o<16;o<<=1) vmax = fmaxf(vmax, __shfl_xor(vmax,o));
      if((lane&15)==0) pmax[row][w] = vmax;
    }
  __syncthreads();
  if(tid < 80){
    float m = pmax[tid][0];
    #pragma unroll
    for(int ww=1;ww<8;ww++) m = fmaxf(m, pmax[tid][ww]);
    mfin[tid] = m;
  }
  __syncthreads();
  #pragma unroll
  for(int i=0;i<5;i++)
    #pragma unroll
    for(int rr=0;rr<4;rr++){
      int row = i*16 + (lane>>4)*4 + rr;
      float m = mfin[row];
      float ssum = 0.f;
      #pragma unroll
      for(int j=0;j<4;j++){
        float e = mk[j]? __expf(acc[i][j][rr] - m) : 0.f;
        acc[i][j][rr] = e;
        ssum += e;
      }
      #pragma unroll
      for(int o=1;o<16;o<<=1) ssum += __shfl_xor(ssum,o);
      if((lane&15)==0) psum[row][w] = ssum;
    }
  __syncthreads();
  if(tid < 80){
    float ss = 0.f;
    #pragma unroll
    for(int ww=0;ww<8;ww++) ss += psum[tid][ww];
    sinv[tid] = 1.f/ss;
  }
  __syncthreads();
  u16* Pp = P_b + (size_t)gb*160*S_ + (size_t)rbase*S_;
  for(int i=0;i<5;i++){
    #pragma unroll
    for(int rr=0;rr<4;rr++){
      int r16 = (lane>>4)*4 + rr;
      float inv = sinv[i*16 + r16];
      #pragma unroll
      for(int j=0;j<4;j++){
        int col = w*64 + j*16 + (lane&15);
        pst[r16][col] = f2bf(acc[i][j][rr]*inv);
      }
    }
    __syncthreads();
    for(int e=tid; e<16*256; e+=512){
      int r16 = e>>8, c = e&255;
      u32 v = *(const u32*)&pst[r16][2*c];
      *(u32*)(Pp + (size_t)(i*16 + r16)*S_ + 2*c) = v;
    }
    __syncthreads();
  }
}

// ---- ctx = P @ ehs : xcd-swizzled; 2-stage software-pipelined K-loop (R15) ----
__global__ __launch_bounds__(512) void k_ctx2(const u16* __restrict__ ehsT,
                                              const u16* __restrict__ P_b,
                                              u16* __restrict__ ctx_b){
  int g = blockIdx.x;
  int x = g & 7, sl = g >> 3;
  int b = x*16 + (sl>>2);
  int var = sl & 3; int nh = var>>1, mha = var&1;
  int tid = threadIdx.x, lane = tid&63, w = tid>>6;
  __shared__ u16 ct[80][392];
  int nbase = nh*384 + w*48;
  const u16* Pp = P_b + (size_t)(2*b+mha)*160*S_;
  f32x4 acc[10][3];
  #pragma unroll
  for(int i=0;i<10;i++)
    #pragma unroll
    for(int j=0;j<3;j++) acc[i][j] = (f32x4){0.f,0.f,0.f,0.f};

  bhalf8 aA[10], bA[3], aB[10], bB[3];
  {
    int ko = (lane>>4)*8;
    #pragma unroll
    for(int t2=0;t2<3;t2++)
      bA[t2] = *(const bhalf8*)(ehsT + ((size_t)b*H_ + nbase + t2*16 + (lane&15))*S_ + ko);
    #pragma unroll
    for(int i=0;i<10;i++)
      aA[i] = *(const bhalf8*)(Pp + (size_t)(i*16 + (lane&15))*S_ + ko);
  }
  for(int kt=0; kt<16; kt+=2){
    {
      int ko = (kt+1)*32 + (lane>>4)*8;
      #pragma unroll
      for(int t2=0;t2<3;t2++)
        bB[t2] = *(const bhalf8*)(ehsT + ((size_t)b*H_ + nbase + t2*16 + (lane&15))*S_ + ko);
      #pragma unroll
      for(int i=0;i<10;i++)
        aB[i] = *(const bhalf8*)(Pp + (size_t)(i*16 + (lane&15))*S_ + ko);
    }
    #pragma unroll
    for(int i=0;i<10;i++)
      #pragma unroll
      for(int t2=0;t2<3;t2++) acc[i][t2] = mfma16(aA[i], bA[t2], acc[i][t2]);
    if(kt+2 < 16){
      int ko = (kt+2)*32 + (lane>>4)*8;
      #pragma unroll
      for(int t2=0;t2<3;t2++)
        bA[t2] = *(const bhalf8*)(ehsT + ((size_t)b*H_ + nbase + t2*16 + (lane&15))*S_ + ko);
      #pragma unroll
      for(int i=0;i<10;i++)
        aA[i] = *(const bhalf8*)(Pp + (size_t)(i*16 + (lane&15))*S_ + ko);
    }
    #pragma unroll
    for(int i=0;i<10;i++)
      #pragma unroll
      for(int t2=0;t2<3;t2++) acc[i][t2] = mfma16(aB[i], bB[t2], acc[i][t2]);
  }
  u16* Cp = ctx_b + (size_t)(2*b+mha)*160*H_ + nh*384;
  #pragma unroll
  for(int half=0; half<2; half++){
    __syncthreads();
    #pragma unroll
    for(int i=0;i<5;i++)
      #pragma unroll
      for(int t2=0;t2<3;t2++)
        #pragma unroll
        for(int rr=0;rr<4;rr++){
          int rloc = i*16 + (lane>>4)*4 + rr;
          int cl = w*48 + t2*16 + (lane&15);
          ct[rloc][cl] = f2bf(acc[half*5+i][t2][rr]);
        }
    __syncthreads();
    for(int e=tid; e<80*192; e+=512){
      int r = e/192, c2 = (e%192)*2;
      u32 v = (u32)ct[r][c2] | ((u32)ct[r][c2+1]<<16);
      *(u32*)(Cp + (size_t)(half*80 + r)*H_ + c2) = v;
    }
  }
}

// ---------------- out = (ctx@Wv^T + bv) @ Wout^T  ----------------
__global__ __launch_bounds__(512) void k_out(const u16* __restrict__ ctx_b,
                                             const u16* __restrict__ Wv_b,
                                             const u16* __restrict__ Wo_b,
                                             const float* __restrict__ taBin,
                                             const float* __restrict__ iaBin,
                                             float* __restrict__ out_t,
                                             float* __restrict__ out_i){
  int gb = blockIdx.x; int b = gb>>1, mha = gb&1;
  int tid = threadIdx.x, lane = tid&63, w = tid>>6;
  const float* bIn = mha? iaBin : taBin;
  const u16* Wv = Wv_b + (size_t)mha*H_*H_;
  const u16* Wo = Wo_b + (size_t)mha*H_*H_;
  const u16* Cp = ctx_b + (size_t)gb*160*H_;
  __shared__ u16 vt[32][784];
  int hd0 = w*HD_;
  {
    f32x4 acc[2][6];
    #pragma unroll
    for(int i=0;i<2;i++)
      #pragma unroll
      for(int j=0;j<6;j++) acc[i][j] = (f32x4){0.f,0.f,0.f,0.f};
    for(int kt=0;kt<24;kt++){
      int ko = kt*32 + (lane>>4)*8;
      bhalf8 a[2];
      #pragma unroll
      for(int mt=0;mt<2;mt++){
        int trow = mt*16 + (lane&15);
        a[mt] = *(const bhalf8*)(Cp + (size_t)(w*T_ + trow)*H_ + ko);
      }
      bhalf8 bb[6];
      #pragma unroll
      for(int j=0;j<6;j++){
        int row = hd0 + j*16 + (lane&15);
        bb[j] = *(const bhalf8*)(Wv + (size_t)row*H_ + ko);
      }
      #pragma unroll
      for(int mt=0;mt<2;mt++)
        #pragma unroll
        for(int j=0;j<6;j++) acc[mt][j] = mfma16(a[mt], bb[j], acc[mt][j]);
    }
    #pragma unroll
    for(int mt=0;mt<2;mt++)
      #pragma unroll
      for(int j=0;j<6;j++){
        int col = j*16 + (lane&15);
        float bv = bIn[2*H_ + hd0 + col];
        #pragma unroll
        for(int rr=0;rr<4;rr++){
          int trow = mt*16 + (lane>>4)*4 + rr;
          vt[trow][hd0 + col] = f2bf(acc[mt][j][rr] + bv);
        }
      }
  }
  __syncthreads();
  {
    f32x4 o[2][6];
    #pragma unroll
    for(int i=0;i<2;i++)
      #pragma unroll
      for(int j=0;j<6;j++) o[i][j] = (f32x4){0.f,0.f,0.f,0.f};
    for(int kt=0;kt<24;kt++){
      int ko = kt*32 + (lane>>4)*8;
      bhalf8 a[2];
      #pragma unroll
      for(int mt=0;mt<2;mt++)
        a[mt] = *(const bhalf8*)(&vt[mt*16 + (lane&15)][ko]);
      bhalf8 bb[6];
      #pragma unroll
      for(int j=0;j<6;j++){
        int row = (w*6+j)*16 + (lane&15);
        bb[j] = *(const bhalf8*)(Wo + (size_t)row*H_ + ko);
      }
      #pragma unroll
      for(int mt=0;mt<2;mt++)
        #pragma unroll
        for(int j=0;j<6;j++) o[mt][j] = mfma16(a[mt], bb[j], o[mt][j]);
    }
    float* op = (mha? out_i : out_t) + (size_t)b*T_*H_;
    #pragma unroll
    for(int mt=0;mt<2;mt++)
      #pragma unroll
      for(int j=0;j<6;j++){
        int col = (w*6+j)*16 + (lane&15);
        #pragma unroll
        for(int rr=0;rr<4;rr++){
          int trow = mt*16 + (lane>>4)*4 + rr;
          if(trow < T_) op[(size_t)trow*H_ + col] = o[mt][j][rr];
        }
      }
  }
}

// ---- cap = relu(LN(comb @ laW^T + laB)), comb blended in-register ----
__global__ __launch_bounds__(512) void k_cap3(const float* __restrict__ out_t,
                                              const float* __restrict__ out_i,
                                              const float* __restrict__ taBout,
                                              const float* __restrict__ iaBout,
                                              const float* __restrict__ rel,
                                              const u16* __restrict__ laW_b,
                                              const float* __restrict__ laB,
                                              const float* __restrict__ laG,
                                              const float* __restrict__ laBe,
                                              float* __restrict__ cap){
  int blk = blockIdx.x; int row0 = blk*16;
  int tid = threadIdx.x, lane = tid&63, w = tid>>6;
  __shared__ float sy[16][776];
  __shared__ float sbo[H_], sbi[H_];
  for(int j=tid;j<H_;j+=512){ sbo[j]=taBout[j]; sbi[j]=iaBout[j]; }
  __syncthreads();
  int arow = row0 + (lane&15);
  float beta = rel[arow/T_];
  f32x4 acc[6];
  #pragma unroll
  for(int j=0;j<6;j++) acc[j] = (f32x4){0.f,0.f,0.f,0.f};
  for(int kt=0;kt<24;kt++){
    int ko = kt*32 + (lane>>4)*8;
    const float* tp = out_t + (size_t)arow*H_ + ko;
    const float* ip = out_i + (size_t)arow*H_ + ko;
    float4 t0 = *(const float4*)tp, t1 = *(const float4*)(tp+4);
    float4 i0 = *(const float4*)ip, i1 = *(const float4*)(ip+4);
    float v[8];
    v[0] = beta*(i0.x+sbi[ko+0]) + (1.f-beta)*(t0.x+sbo[ko+0]);
    v[1] = beta*(i0.y+sbi[ko+1]) + (1.f-beta)*(t0.y+sbo[ko+1]);
    v[2] = beta*(i0.z+sbi[ko+2]) + (1.f-beta)*(t0.z+sbo[ko+2]);
    v[3] = beta*(i0.w+sbi[ko+3]) + (1.f-beta)*(t0.w+sbo[ko+3]);
    v[4] = beta*(i1.x+sbi[ko+4]) + (1.f-beta)*(t1.x+sbo[ko+4]);
    v[5] = beta*(i1.y+sbi[ko+5]) + (1.f-beta)*(t1.y+sbo[ko+5]);
    v[6] = beta*(i1.z+sbi[ko+6]) + (1.f-beta)*(t1.z+sbo[ko+6]);
    v[7] = beta*(i1.w+sbi[ko+7]) + (1.f-beta)*(t1.w+sbo[ko+7]);
    U8 u;
    u.u[0]=cvtpk(v[0],v[1]); u.u[1]=cvtpk(v[2],v[3]);
    u.u[2]=cvtpk(v[4],v[5]); u.u[3]=cvtpk(v[6],v[7]);
    bhalf8 a = u.s;
    bhalf8 bb[6];
    #pragma unroll
    for(int j=0;j<6;j++){
      int row = (w*6+j)*16 + (lane&15);
      bb[j] = *(const bhalf8*)(laW_b + (size_t)row*H_ + ko);
    }
    #pragma unroll
    for(int j=0;j<6;j++) acc[j] = mfma16(a, bb[j], acc[j]);
  }
  #pragma unroll
  for(int j=0;j<6;j++){
    int c = (w*6+j)*16 + (lane&15);
    float lb = laB[c];
    #pragma unroll
    for(int rr=0;rr<4;rr++){
      int r = (lane>>4)*4 + rr;
      sy[r][c] = acc[j][rr] + lb;
    }
  }
  __syncthreads();
  for(int ri=0; ri<2; ri++){
    int r = w*2 + ri;
    float v[12];
    float s = 0.f;
    #pragma unroll
    for(int i=0;i<12;i++){ v[i] = sy[r][lane + 64*i]; s += v[i]; }
    s = wsum(s);
    float mean = s/(float)H_;
    float pv = 0.f;
    #pragma unroll
    for(int i=0;i<12;i++){ float d = v[i]-mean; pv += d*d; }
    pv = wsum(pv);
    float rstd = rsqrtf(pv/(float)H_ + 1e-5f);
    float* cp = cap + (size_t)(row0 + r)*H_;
    #pragma unroll
    for(int i=0;i<12;i++){
      int c = lane + 64*i;
      float o = (v[i]-mean)*rstd*laG[c] + laBe[c];
      cp[c] = (o>0.f)? o : 0.f;
    }
  }
}

// ------- fused quality head -------
__global__ __launch_bounds__(512) void k_quality2(const float* __restrict__ cap,
                                                  const u16* __restrict__ qW1_b,
                                                  const float* __restrict__ qB1,
                                                  const float* __restrict__ qG,
                                                  const float* __restrict__ qBe,
                                                  const float* __restrict__ qW2,
                                                  const float* __restrict__ qB2,
                                                  float* __restrict__ outq){
  const int H2 = H_/2;
  int b0 = blockIdx.x*16;
  int tid = threadIdx.x, lane = tid&63, w = tid>>6;
  __shared__ u16 sm_a[16][772];
  __shared__ float sy[16][388];
  for(int e=tid; e<16*H_; e+=512){
    int r = e/H_, c = e%H_;
    const float* cp = cap + ((size_t)(b0+r)*T_)*H_ + c;
    float s = 0.f;
    #pragma unroll
    for(int t=0;t<T_;t++) s += cp[(size_t)t*H_];
    sm_a[r][c] = f2bf(s*(1.f/(float)T_));
  }
  __syncthreads();
  f32x4 acc[3];
  #pragma unroll
  for(int j=0;j<3;j++) acc[j] = (f32x4){0.f,0.f,0.f,0.f};
  for(int kt=0;kt<24;kt++){
    int ko = kt*32 + (lane>>4)*8;
    bhalf8 a = *(const bhalf8*)(&sm_a[lane&15][ko]);
    bhalf8 bb[3];
    #pragma unroll
    for(int j=0;j<3;j++){
      int row = (w*3+j)*16 + (lane&15);
      bb[j] = *(const bhalf8*)(qW1_b + (size_t)row*H_ + ko);
    }
    #pragma unroll
    for(int j=0;j<3;j++) acc[j] = mfma16(a, bb[j], acc[j]);
  }
  #pragma unroll
  for(int j=0;j<3;j++){
    int c = (w*3+j)*16 + (lane&15);
    float q1 = qB1[c];
    #pragma unroll
    for(int rr=0;rr<4;rr++){
      int r = (lane>>4)*4 + rr;
      sy[r][c] = acc[j][rr] + q1;
    }
  }
  __syncthreads();
  for(int ri=0; ri<2; ri++){
    int r = w*2 + ri;
    float v[6]; float s = 0.f;
    #pragma unroll
    for(int i=0;i<6;i++){ v[i] = sy[r][lane + 64*i]; s += v[i]; }
    s = wsum(s);
    float mean = s/(float)H2;
    float pv = 0.f;
    #pragma unroll
    for(int i=0;i<6;i++){ float d = v[i]-mean; pv += d*d; }
    pv = wsum(pv);
    float rstd = rsqrtf(pv/(float)H2 + 1e-5f);
    float dot = 0.f;
    #pragma unroll
    for(int i=0;i<6;i++){
      int c = lane + 64*i;
      float u = (v[i]-mean)*rstd*qG[c] + qBe[c];
      u = (u>0.f)? u : 0.f;
      dot += u*qW2[c];
    }
    dot = wsum(dot);
    if(lane==0){
      float z = dot + qB2[0];
      outq[b0+r] = 1.f/(1.f+__expf(-z));
    }
  }
}

extern "C" void kernel_launch(void* const* d_in, const int* in_sizes, int n_in,
                              void* d_out, int out_size, void* d_ws, size_t ws_size,
                              hipStream_t stream){
  const float* ehs    = (const float*)d_in[0];
  const float* rel    = (const float*)d_in[1];
  const float* tW1    = (const float*)d_in[3];
  const float* tb1    = (const float*)d_in[4];
  const float* tg     = (const float*)d_in[5];
  const float* tbe    = (const float*)d_in[6];
  const float* tW2    = (const float*)d_in[7];
  const float* tb2    = (const float*)d_in[8];
  const float* iW1    = (const float*)d_in[9];
  const float* ib1    = (const float*)d_in[10];
  const float* ig     = (const float*)d_in[11];
  const float* ibe    = (const float*)d_in[12];
  const float* iW2    = (const float*)d_in[13];
  const float* ib2    = (const float*)d_in[14];
  const float* taWin  = (const float*)d_in[15];
  const float* taBin  = (const float*)d_in[16];
  const float* taWout = (const float*)d_in[17];
  const float* taBout = (const float*)d_in[18];
  const float* iaWin  = (const float*)d_in[19];
  const float* iaBin  = (const float*)d_in[20];
  const float* iaWout = (const float*)d_in[21];
  const float* iaBout = (const float*)d_in[22];
  const float* laW    = (const float*)d_in[23];
  const float* laB    = (const float*)d_in[24];
  const float* laG    = (const float*)d_in[25];
  const float* laBe   = (const float*)d_in[26];
  const float* qW1    = (const float*)d_in[27];
  const float* qB1    = (const float*)d_in[28];
  const float* qG     = (const float*)d_in[29];
  const float* qBe    = (const float*)d_in[30];
  const float* qW2    = (const float*)d_in[31];
  const float* qB2    = (const float*)d_in[32];
  const int* smask    = (const int*)d_in[33];
  const int* imask    = (const int*)d_in[34];

  char* p = (char*)d_ws;
  auto take = [&](size_t bytes)->char*{
    char* r = p; p += (bytes + 255) & ~(size_t)255; return r;
  };
  float* st      = (float*)take((size_t)B_*H_*4);
  float* si      = (float*)take((size_t)B_*H_*4);
  u16*  pt_b     = (u16*)take((size_t)B_*H_*2);
  u16*  pi_b     = (u16*)take((size_t)B_*H_*2);
  u16*  query_b  = (u16*)take((size_t)B_*32*H_*2);
  u16*  WkT      = (u16*)take((size_t)2*H_*H_*2);
  // NOTE: the next 12 matrices are contiguous — k_cvtall relies on it
  u16*  Wq_b     = (u16*)take((size_t)2*H_*H_*2);
  u16*  Wv_b     = (u16*)take((size_t)2*H_*H_*2);
  u16*  Wo_b     = (u16*)take((size_t)2*H_*H_*2);
  u16*  laW_b    = (u16*)take((size_t)H_*H_*2);
  u16*  tW1_b    = (u16*)take((size_t)H_*H_*2);
  u16*  tW2_b    = (u16*)take((size_t)H_*H_*2);
  u16*  iW1_b    = (u16*)take((size_t)H_*H_*2);
  u16*  iW2_b    = (u16*)take((size_t)H_*H_*2);
  u16*  qW1_b    = (u16*)take((size_t)(H_/2)*H_*2);
  float* bias_ws = (float*)take((size_t)B_*2*160*4);
  float* pool_f  = (float*)take((size_t)2*B_*8*H_*4);
  u16*  U_b      = (u16*)take((size_t)B_*2*160*H_*2);   // aliased by ctx_b
  u16*  P_b      = (u16*)take((size_t)B_*2*160*S_*2);
  float* out_t   = (float*)take((size_t)B_*T_*H_*4);
  float* out_i   = (float*)take((size_t)B_*T_*H_*4);
  u16*  ehs_b    = (u16*)take((size_t)B_*S_*H_*2);
  u16*  ehsT     = (u16*)take((size_t)B_*H_*S_*2);
  u16*  ctx_b    = U_b;

  // ehs layout prep + fused masked pool partials
  hipLaunchKernelGGL(k_prep, dim3(B_*96), dim3(256), 0, stream,
                     ehs, smask, imask, ehs_b, ehsT, pool_f);

  // ALL weight conversions in one launch
  const int NP = (H_*H_)/2;
  const int cvtallg = (11*NP + NP/2 + 255)/256;
  hipLaunchKernelGGL(k_cvtall, dim3(cvtallg), dim3(256), 0, stream,
                     taWin, iaWin, taWin + 2*H_*H_, iaWin + 2*H_*H_,
                     taWout, iaWout, laW, tW1, tW2, iW1, iW2, qW1, Wq_b);
  hipLaunchKernelGGL(k_wkt, dim3(1152), dim3(256), 0, stream, taWin, iaWin, WkT);

  // pooling finalize + seeds + query
  hipLaunchKernelGGL(k_poolfin, dim3(B_), dim3(256), 0, stream,
                     pool_f, smask, imask, pt_b, pi_b);
  hipLaunchKernelGGL(k_seed2, dim3(B_/8), dim3(512), 0, stream,
                     pt_b, pi_b, tW1_b, tb1, tg, tbe, tW2_b, tb2,
                     iW1_b, ib1, ig, ibe, iW2_b, ib2, st, si);
  hipLaunchKernelGGL(k_query, dim3(B_), dim3(256), 0, stream, st, si, rel, query_b);

  // attention pipeline
  hipLaunchKernelGGL(k_qu,      dim3(B_*2), dim3(512), 0, stream,
                     query_b, Wq_b, WkT, taBin, iaBin, U_b, bias_ws);
  hipLaunchKernelGGL(k_scores2, dim3(B_*4), dim3(512), 0, stream, ehs_b, U_b, bias_ws, smask, imask, P_b);
  hipLaunchKernelGGL(k_ctx2,    dim3(B_*4), dim3(512), 0, stream, ehsT, P_b, ctx_b);
  hipLaunchKernelGGL(k_out,     dim3(B_*2), dim3(512), 0, stream, ctx_b, Wv_b, Wo_b, taBin, iaBin, out_t, out_i);

  // epilogue
  float* cap = (float*)d_out;
  hipLaunchKernelGGL(k_cap3, dim3((B_*T_)/16), dim3(512), 0, stream,
                     out_t, out_i, taBout, iaBout, rel, laW_b, laB, laG, laBe, cap);
  hipLaunchKernelGGL(k_quality2, dim3(B_/16), dim3(512), 0, stream,
                     cap, qW1_b, qB1, qG, qBe, qW2, qB2, cap + (size_t)B_*T_*H_);
}

// Round 16
// 694.523 us; speedup vs baseline: 1.2678x; 1.2678x over previous
//
#include <hip/hip_runtime.h>
#include <hip/hip_bf16.h>
#include <math.h>

#define B_  128
#define S_  512
#define H_  768
#define NH_ 8
#define T_  20
#define HD_ 96

typedef unsigned short u16;
typedef unsigned int   u32;

typedef __attribute__((ext_vector_type(8))) short bhalf8;
typedef __attribute__((ext_vector_type(4))) float f32x4;

union U8 { bhalf8 s; u32 u[4]; };

__device__ __forceinline__ f32x4 mfma16(bhalf8 a, bhalf8 b, f32x4 c){
  return __builtin_amdgcn_mfma_f32_16x16x32_bf16(a, b, c, 0, 0, 0);
}
__device__ __forceinline__ u32 cvtpk(float lo, float hi){
  u32 r; asm volatile("v_cvt_pk_bf16_f32 %0, %1, %2" : "=v"(r) : "v"(lo), "v"(hi));
  return r;
}
__device__ __forceinline__ float wsum(float v){
  #pragma unroll
  for(int o=32;o;o>>=1) v += __shfl_xor(v,o);
  return v;
}
__device__ __forceinline__ u16 f2bf(float f){
  u32 u = __float_as_uint(f);
  u32 r = (u + 0x7fffu + ((u>>16)&1u)) >> 16;
  return (u16)r;
}
__device__ __forceinline__ float bf2f(u32 bits){
  return __uint_as_float(bits<<16);
}

// ------ ALL weight conversions in ONE launch (dst buffers contiguous in ws) ------
__global__ void k_cvtall(const float* __restrict__ s0, const float* __restrict__ s1,
                         const float* __restrict__ s2, const float* __restrict__ s3,
                         const float* __restrict__ s4, const float* __restrict__ s5,
                         const float* __restrict__ s6, const float* __restrict__ s7,
                         const float* __restrict__ s8, const float* __restrict__ s9,
                         const float* __restrict__ s10, const float* __restrict__ s11,
                         u16* __restrict__ dst){
  const int NP = (H_*H_)/2;
  int idx = blockIdx.x*256 + threadIdx.x;
  int seg, po;
  if(idx < 11*NP){ seg = idx / NP; po = idx - seg*NP; }
  else           { seg = 11; po = idx - 11*NP; if(po >= NP/2) return; }
  const float* src =
    seg==0? s0 : seg==1? s1 : seg==2? s2 : seg==3? s3 : seg==4? s4 : seg==5? s5 :
    seg==6? s6 : seg==7? s7 : seg==8? s8 : seg==9? s9 : seg==10? s10 : s11;
  u32 r = cvtpk(src[2*po], src[2*po+1]);
  *(u32*)(dst + (size_t)seg*(H_*H_) + 2*po) = r;
}

// ------- ehs -> ehs_b + ehsT (bf16), 64x64 tiles; ALSO masked pool partials -------
__global__ __launch_bounds__(256) void k_prep(const float* __restrict__ ehs,
                                              const int* __restrict__ sm,
                                              const int* __restrict__ im,
                                              u16* __restrict__ ehs_b,
                                              u16* __restrict__ ehsT,
                                              float* __restrict__ pool_part){
  int blk = blockIdx.x;
  int b  = blk / 96;
  int r  = blk % 96;
  int sb = r / 12, hb = r % 12;
  int s0 = sb*64, h0 = hb*64;
  __shared__ float tile[64][65];
  __shared__ float marr[2][64];
  __shared__ float red[2][4][64];
  int t = threadIdx.x;
  if(t < 64)       marr[0][t]    = (float)sm[b*S_ + s0 + t];
  else if(t < 128) marr[1][t-64] = (float)im[b*S_ + s0 + (t-64)];
  const float* src = ehs + ((size_t)b*S_ + s0)*H_ + h0;
  #pragma unroll
  for(int p2=0;p2<4;p2++){
    int row = p2*16 + (t>>4);
    int c4  = (t&15)*4;
    float4 v = *(const float4*)(src + (size_t)row*H_ + c4);
    tile[row][c4+0]=v.x; tile[row][c4+1]=v.y; tile[row][c4+2]=v.z; tile[row][c4+3]=v.w;
    u32 lo = cvtpk(v.x, v.y), hi2 = cvtpk(v.z, v.w);
    u32* dst = (u32*)(ehs_b + ((size_t)b*S_ + s0 + row)*H_ + h0 + c4);
    dst[0]=lo; dst[1]=hi2;
  }
  __syncthreads();
  #pragma unroll
  for(int p2=0;p2<4;p2++){
    int hr = p2*16 + (t>>4);
    int sg2 = (t&15)*4;
    float a0 = tile[sg2+0][hr], a1 = tile[sg2+1][hr];
    float a2 = tile[sg2+2][hr], a3 = tile[sg2+3][hr];
    u32 lo = cvtpk(a0,a1), hi2 = cvtpk(a2,a3);
    u32* dst = (u32*)(ehsT + ((size_t)b*H_ + h0 + hr)*S_ + s0 + sg2);
    dst[0]=lo; dst[1]=hi2;
  }
  int h = t & 63, sg = t >> 6;
  float ts=0.f, is=0.f;
  #pragma unroll
  for(int k=0;k<16;k++){
    float v = tile[sg*16+k][h];
    ts += v*marr[0][sg*16+k];
    is += v*marr[1][sg*16+k];
  }
  red[0][sg][h]=ts; red[1][sg][h]=is;
  __syncthreads();
  if(sg==0){
    float tsum = red[0][0][h]+red[0][1][h]+red[0][2][h]+red[0][3][h];
    float isum = red[1][0][h]+red[1][1][h]+red[1][2][h]+red[1][3][h];
    pool_part[(((size_t)0*B_+b)*8+sb)*H_ + h0 + h] = tsum;
    pool_part[(((size_t)1*B_+b)*8+sb)*H_ + h0 + h] = isum;
  }
}

// ------ finalize pooling ------
__global__ __launch_bounds__(256) void k_poolfin(const float* __restrict__ pool_part,
                                                 const int* __restrict__ sm,
                                                 const int* __restrict__ im,
                                                 u16* __restrict__ pt_b,
                                                 u16* __restrict__ pi_b){
  int b = blockIdx.x, tid = threadIdx.x, lane = tid&63, w = tid>>6;
  __shared__ float red2[2][4];
  float tl=0.f, il=0.f;
  for(int s=tid; s<S_; s+=256){ tl += (float)sm[b*S_+s]; il += (float)im[b*S_+s]; }
  tl = wsum(tl); il = wsum(il);
  if(lane==0){ red2[0][w]=tl; red2[1][w]=il; }
  __syncthreads();
  float tlen = fmaxf(red2[0][0]+red2[0][1]+red2[0][2]+red2[0][3], 1e-9f);
  float ilen = fmaxf(red2[1][0]+red2[1][1]+red2[1][2]+red2[1][3], 1e-9f);
  for(int h=tid; h<H_; h+=256){
    float ts=0.f, is2=0.f;
    #pragma unroll
    for(int sb=0; sb<8; sb++){
      ts  += pool_part[(((size_t)0*B_+b)*8+sb)*H_ + h];
      is2 += pool_part[(((size_t)1*B_+b)*8+sb)*H_ + h];
    }
    pt_b[b*H_+h] = f2bf(ts/tlen);
    pi_b[b*H_+h] = f2bf(is2/ilen);
  }
}

// ---------------- WkT[mha][n][k] = Wk[k][n] (bf16) ----------------
__global__ void k_wkt(const float* __restrict__ taWin, const float* __restrict__ iaWin,
                      u16* __restrict__ WkT){
  int blk = blockIdx.x; int mha = blk/576; int t = blk%576;
  const float* Wk = (mha? iaWin : taWin) + (size_t)H_*H_;
  int bx = t%24, by = t/24;
  __shared__ float tile[32][33];
  int tx = threadIdx.x & 31, ty = threadIdx.x >> 5;
  for(int rr=ty; rr<32; rr+=8) tile[rr][tx] = Wk[(size_t)(by*32+rr)*H_ + bx*32+tx];
  __syncthreads();
  u16* dst = WkT + (size_t)mha*H_*H_;
  for(int rr=ty; rr<32; rr+=8) dst[(size_t)(bx*32+rr)*H_ + by*32+tx] = f2bf(tile[tx][rr]);
}

// ------ fused seed proj BOTH modalities ------
__global__ __launch_bounds__(512) void k_seed2(const u16* __restrict__ pt_b,
                                               const u16* __restrict__ pi_b,
                                               const u16* __restrict__ tW1_b, const float* __restrict__ tb1,
                                               const float* __restrict__ tg,  const float* __restrict__ tbe,
                                               const u16* __restrict__ tW2_b, const float* __restrict__ tb2,
                                               const u16* __restrict__ iW1_b, const float* __restrict__ ib1,
                                               const float* __restrict__ ig,  const float* __restrict__ ibe,
                                               const u16* __restrict__ iW2_b, const float* __restrict__ ib2,
                                               float* __restrict__ st, float* __restrict__ si){
  int which = blockIdx.x >= (B_/16);
  int row0 = (blockIdx.x - which*(B_/16))*16;
  const u16* x_b  = which? pi_b  : pt_b;
  const u16* W1_b = which? iW1_b : tW1_b;
  const float* b1 = which? ib1 : tb1;
  const float* g  = which? ig  : tg;
  const float* be = which? ibe : tbe;
  const u16* W2_b = which? iW2_b : tW2_b;
  const float* b2 = which? ib2 : tb2;
  float* out      = which? si : st;
  int tid = threadIdx.x, lane = tid&63, w = tid>>6;
  __shared__ u16 ln[16][772];
  f32x4 acc[6];
  #pragma unroll
  for(int j=0;j<6;j++) acc[j] = (f32x4){0.f,0.f,0.f,0.f};
  for(int kt=0;kt<24;kt++){
    int ko = kt*32 + (lane>>4)*8;
    bhalf8 a = *(const bhalf8*)(x_b + (size_t)(row0 + (lane&15))*H_ + ko);
    bhalf8 bb[6];
    #pragma unroll
    for(int j=0;j<6;j++){
      int row = (w*6+j)*16 + (lane&15);
      bb[j] = *(const bhalf8*)(W1_b + (size_t)row*H_ + ko);
    }
    #pragma unroll
    for(int j=0;j<6;j++) acc[j] = mfma16(a, bb[j], acc[j]);
  }
  #pragma unroll
  for(int j=0;j<6;j++){
    int c = (w*6+j)*16 + (lane&15);
    float bv = b1[c];
    #pragma unroll
    for(int rr=0;rr<4;rr++){
      int r = (lane>>4)*4 + rr;
      float v = acc[j][rr] + bv;
      ln[r][c] = f2bf((v>=0.f)? v : 0.01f*v);
    }
  }
  __syncthreads();
  for(int ri=0; ri<2; ri++){
    int r = w*2 + ri;
    float v[12]; float s = 0.f;
    #pragma unroll
    for(int i=0;i<12;i++){ v[i] = bf2f(ln[r][lane + 64*i]); s += v[i]; }
    s = wsum(s);
    float mean = s/(float)H_;
    float pv = 0.f;
    #pragma unroll
    for(int i=0;i<12;i++){ float d = v[i]-mean; pv += d*d; }
    pv = wsum(pv);
    float rstd = rsqrtf(pv/(float)H_ + 1e-5f);
    #pragma unroll
    for(int i=0;i<12;i++){
      int c = lane + 64*i;
      ln[r][c] = f2bf((v[i]-mean)*rstd*g[c] + be[c]);
    }
  }
  __syncthreads();
  f32x4 o[6];
  #pragma unroll
  for(int j=0;j<6;j++) o[j] = (f32x4){0.f,0.f,0.f,0.f};
  for(int kt=0;kt<24;kt++){
    int ko = kt*32 + (lane>>4)*8;
    bhalf8 a = *(const bhalf8*)(&ln[lane&15][ko]);
    bhalf8 bb[6];
    #pragma unroll
    for(int j=0;j<6;j++){
      int row = (w*6+j)*16 + (lane&15);
      bb[j] = *(const bhalf8*)(W2_b + (size_t)row*H_ + ko);
    }
    #pragma unroll
    for(int j=0;j<6;j++) o[j] = mfma16(a, bb[j], o[j]);
  }
  #pragma unroll
  for(int j=0;j<6;j++){
    int c = (w*6+j)*16 + (lane&15);
    float bv = b2[c];
    #pragma unroll
    for(int rr=0;rr<4;rr++){
      int r = (lane>>4)*4 + rr;
      out[(size_t)(row0 + r)*H_ + c] = o[j][rr] + bv;
    }
  }
}

// ---------------- query (padded to 32 rows, bf16) ----------------
__global__ void k_query(const float* __restrict__ st, const float* __restrict__ si,
                        const float* __restrict__ rel, u16* __restrict__ query_b){
  int b = blockIdx.x; int tid = threadIdx.x;
  float a = rel[b];
  const float c = 9.210340371976184f/(float)H_;
  for(int t=0;t<32;t++){
    for(int h=tid;h<H_;h+=256){
      float val = 0.f;
      if(t < T_){
        float ang = (float)t * __expf(-(float)(h & ~1) * c);
        float pe  = (h&1)? __cosf(ang) : __sinf(ang);
        val = a*si[b*H_+h] + (1.f-a)*st[b*H_+h] + pe;
      }
      query_b[(size_t)b*32*H_ + t*H_ + h] = f2bf(val);
    }
  }
}

// ---- FUSED qh+U: qh = query@Wq^T+bq (LDS only), then U = qh_h@Wk_h + bias ----
__global__ __launch_bounds__(512) void k_qu(const u16* __restrict__ query_b,
                                            const u16* __restrict__ Wq_b,
                                            const u16* __restrict__ WkT,
                                            const float* __restrict__ taBin,
                                            const float* __restrict__ iaBin,
                                            u16* __restrict__ U_b,
                                            float* __restrict__ bias_ws){
  int gb = blockIdx.x; int b = gb>>1, mha = gb&1;
  int tid = threadIdx.x, lane = tid&63, w = tid>>6;
  const u16* Q  = query_b + (size_t)b*32*H_;
  const u16* Wq = Wq_b + (size_t)mha*H_*H_;
  const u16* Wk = WkT + (size_t)mha*H_*H_;
  const float* bIn = mha? iaBin : taBin;
  u16* Up = U_b + (size_t)gb*160*H_;
  __shared__ u16 qh_s[32][776];
  __shared__ u16 ut[20][776];
  const float rscale = 0.10206207261596577f;

  {
    f32x4 acc[2][6];
    #pragma unroll
    for(int i=0;i<2;i++)
      #pragma unroll
      for(int j=0;j<6;j++) acc[i][j] = (f32x4){0.f,0.f,0.f,0.f};
    for(int kt=0;kt<24;kt++){
      int ko = kt*32 + (lane>>4)*8;
      bhalf8 a[2];
      #pragma unroll
      for(int mt=0;mt<2;mt++)
        a[mt] = *(const bhalf8*)(Q + (size_t)(mt*16 + (lane&15))*H_ + ko);
      bhalf8 bb[6];
      #pragma unroll
      for(int j=0;j<6;j++){
        int row = (w*6+j)*16 + (lane&15);
        bb[j] = *(const bhalf8*)(Wq + (size_t)row*H_ + ko);
      }
      #pragma unroll
      for(int mt=0;mt<2;mt++)
        #pragma unroll
        for(int j=0;j<6;j++) acc[mt][j] = mfma16(a[mt], bb[j], acc[mt][j]);
    }
    #pragma unroll
    for(int mt=0;mt<2;mt++)
      #pragma unroll
      for(int j=0;j<6;j++){
        int col = (w*6+j)*16 + (lane&15);
        float bq = bIn[col];
        #pragma unroll
        for(int rr=0;rr<4;rr++){
          int row = mt*16 + (lane>>4)*4 + rr;
          qh_s[row][col] = f2bf(acc[mt][j][rr] + bq);
        }
      }
  }
  __syncthreads();

  for(int h=0; h<8; h++){
    int hd0 = h*HD_;
    for(int jn=0; jn<6; jn++){
      int nb = (w*6+jn)*16 + (lane&15);
      bhalf8 bb[3];
      #pragma unroll
      for(int kt=0;kt<3;kt++)
        bb[kt] = *(const bhalf8*)(Wk + (size_t)nb*H_ + hd0 + kt*32 + (lane>>4)*8);
      #pragma unroll
      for(int mt=0; mt<2; mt++){
        bhalf8 a[3];
        #pragma unroll
        for(int kt=0;kt<3;kt++){
          int trow = mt*16 + (lane&15);
          a[kt] = *(const bhalf8*)(&qh_s[trow][hd0 + kt*32 + (lane>>4)*8]);
        }
        f32x4 acc = (f32x4){0.f,0.f,0.f,0.f};
        #pragma unroll
        for(int kt=0;kt<3;kt++) acc = mfma16(a[kt], bb[kt], acc);
        #pragma unroll
        for(int rr=0;rr<4;rr++){
          int trow = mt*16 + (lane>>4)*4 + rr;
          if(trow < T_)
            ut[trow][nb] = f2bf(acc[rr]*rscale);
        }
      }
    }
    __syncthreads();
    for(int e=tid; e<20*384; e+=512){
      int r = e/384, c2 = (e%384)*2;
      u32 v = *(const u32*)&ut[r][c2];
      *(u32*)(Up + (size_t)(h*T_ + r)*H_ + c2) = v;
    }
    __syncthreads();
  }
  if(tid < 160){
    int h = tid/T_, t = tid%T_; int hd0 = h*HD_;
    float p = 0.f;
    for(int d=0; d<HD_; d++)
      p += bf2f(qh_s[t][hd0 + d]) * bIn[H_ + hd0 + d];
    bias_ws[gb*160 + tid] = p*rscale;
  }
}

// ---- scores + single-pass softmax -> P (bf16). grid: 8 XCD x 64; 80 rows/block ----
__global__ __launch_bounds__(512,4) void k_scores2(const u16* __restrict__ ehs_b,
                                                   const u16* __restrict__ U_b,
                                                   const float* __restrict__ bias_ws,
                                                   const int* __restrict__ smask,
                                                   const int* __restrict__ imask,
                                                   u16* __restrict__ P_b){
  int g = blockIdx.x;
  int x = g & 7, sl = g >> 3;
  int b = x*16 + (sl>>2);
  int var = sl & 3; int mha = var>>1, rhalf = var&1;
  int gb = 2*b + mha;
  const int* msk = mha? imask : smask;
  int tid = threadIdx.x, lane = tid&63, w = tid>>6;
  int rbase = rhalf*80;
  __shared__ float sbias[80];
  __shared__ float pmax[80][8];
  __shared__ float psum[80][8];
  __shared__ float mfin[80], sinv[80];
  __shared__ u16 pst[16][520];
  if(tid < 80) sbias[tid] = bias_ws[gb*160 + rbase + tid];
  __syncthreads();
  const u16* Ub = U_b + (size_t)gb*160*H_;
  const u16* Eb = ehs_b + (size_t)b*S_*H_;
  bool mk[4];
  #pragma unroll
  for(int j=0;j<4;j++) mk[j] = msk[b*S_ + w*64 + j*16 + (lane&15)] != 0;

  f32x4 acc[5][4];
  #pragma unroll
  for(int i=0;i<5;i++)
    #pragma unroll
    for(int j=0;j<4;j++) acc[i][j] = (f32x4){0.f,0.f,0.f,0.f};
  for(int kt=0;kt<24;kt++){
    int ko = kt*32 + (lane>>4)*8;
    bhalf8 a[5];
    #pragma unroll
    for(int i=0;i<5;i++)
      a[i] = *(const bhalf8*)(Ub + (size_t)(rbase + i*16 + (lane&15))*H_ + ko);
    bhalf8 bb[4];
    #pragma unroll
    for(int j=0;j<4;j++)
      bb[j] = *(const bhalf8*)(Eb + (size_t)(w*64 + j*16 + (lane&15))*H_ + ko);
    #pragma unroll
    for(int i=0;i<5;i++)
      #pragma unroll
      for(int j=0;j<4;j++) acc[i][j] = mfma16(a[i], bb[j], acc[i][j]);
  }
  #pragma unroll
  for(int i=0;i<5;i++)
    #pragma unroll
    for(int rr=0;rr<4;rr++){
      int row = i*16 + (lane>>4)*4 + rr;
      float bias = sbias[row];
      float vmax = -3e38f;
      #pragma unroll
      for(int j=0;j<4;j++){
        float v = acc[i][j][rr] + bias;
        acc[i][j][rr] = v;
        if(mk[j]) vmax = fmaxf(vmax, v);
      }
      #pragma unroll
      for(int o=1;o<16;o<<=1) vmax = fmaxf(vmax, __shfl_xor(vmax,o));
      if((lane&15)==0) pmax[row][w] = vmax;
    }
  __syncthreads();
  if(tid < 80){
    float m = pmax[tid][0];
    #pragma unroll
    for(int ww=1;ww<8;ww++) m = fmaxf(m, pmax[tid][ww]);
    mfin[tid] = m;
  }
  __syncthreads();
  #pragma unroll
  for(int i=0;i<5;i++)
    #pragma unroll
    for(int rr=0;rr<4;rr++){
      int row = i*16 + (lane>>4)*4 + rr;
      float m = mfin[row];
      float ssum = 0.f;
      #pragma unroll
      for(int j=0;j<4;j++){
        float e = mk[j]? __expf(acc[i][j][rr] - m) : 0.f;
        acc[i][j][rr] = e;
        ssum += e;
      }
      #pragma unroll
      for(int o=1;o<16;o<<=1) ssum += __shfl_xor(ssum,o);
      if((lane&15)==0) psum[row][w] = ssum;
    }
  __syncthreads();
  if(tid < 80){
    float ss = 0.f;
    #pragma unroll
    for(int ww=0;ww<8;ww++) ss += psum[tid][ww];
    sinv[tid] = 1.f/ss;
  }
  __syncthreads();
  u16* Pp = P_b + (size_t)gb*160*S_ + (size_t)rbase*S_;
  for(int i=0;i<5;i++){
    #pragma unroll
    for(int rr=0;rr<4;rr++){
      int r16 = (lane>>4)*4 + rr;
      float inv = sinv[i*16 + r16];
      #pragma unroll
      for(int j=0;j<4;j++){
        int col = w*64 + j*16 + (lane&15);
        pst[r16][col] = f2bf(acc[i][j][rr]*inv);
      }
    }
    __syncthreads();
    for(int e=tid; e<16*256; e+=512){
      int r16 = e>>8, c = e&255;
      u32 v = *(const u32*)&pst[r16][2*c];
      *(u32*)(Pp + (size_t)(i*16 + r16)*S_ + 2*c) = v;
    }
    __syncthreads();
  }
}

// ---- ctx = P @ ehs : grid (xcd-swizzled) over (b, H-half, mha); coalesced writes ----
__global__ __launch_bounds__(512) void k_ctx2(const u16* __restrict__ ehsT,
                                              const u16* __restrict__ P_b,
                                              u16* __restrict__ ctx_b){
  int g = blockIdx.x;
  int x = g & 7, sl = g >> 3;
  int b = x*16 + (sl>>2);
  int var = sl & 3; int nh = var>>1, mha = var&1;
  int tid = threadIdx.x, lane = tid&63, w = tid>>6;
  __shared__ u16 ct[80][392];
  int nbase = nh*384 + w*48;
  const u16* Pp = P_b + (size_t)(2*b+mha)*160*S_;
  f32x4 acc[10][3];
  #pragma unroll
  for(int i=0;i<10;i++)
    #pragma unroll
    for(int j=0;j<3;j++) acc[i][j] = (f32x4){0.f,0.f,0.f,0.f};
  for(int kt=0;kt<16;kt++){
    int ko = kt*32 + (lane>>4)*8;
    bhalf8 bb[3];
    #pragma unroll
    for(int t2=0;t2<3;t2++){
      int n = nbase + t2*16 + (lane&15);
      bb[t2] = *(const bhalf8*)(ehsT + ((size_t)b*H_ + n)*S_ + ko);
    }
    bhalf8 a[10];
    #pragma unroll
    for(int i=0;i<10;i++){
      int row = i*16 + (lane&15);
      a[i] = *(const bhalf8*)(Pp + (size_t)row*S_ + ko);
    }
    #pragma unroll
    for(int i=0;i<10;i++)
      #pragma unroll
      for(int t2=0;t2<3;t2++) acc[i][t2] = mfma16(a[i], bb[t2], acc[i][t2]);
  }
  u16* Cp = ctx_b + (size_t)(2*b+mha)*160*H_ + nh*384;
  #pragma unroll
  for(int half=0; half<2; half++){
    __syncthreads();
    #pragma unroll
    for(int i=0;i<5;i++)
      #pragma unroll
      for(int t2=0;t2<3;t2++)
        #pragma unroll
        for(int rr=0;rr<4;rr++){
          int rloc = i*16 + (lane>>4)*4 + rr;
          int cl = w*48 + t2*16 + (lane&15);
          ct[rloc][cl] = f2bf(acc[half*5+i][t2][rr]);
        }
    __syncthreads();
    for(int e=tid; e<80*192; e+=512){
      int r = e/192, c2 = (e%192)*2;
      u32 v = (u32)ct[r][c2] | ((u32)ct[r][c2+1]<<16);
      *(u32*)(Cp + (size_t)(half*80 + r)*H_ + c2) = v;
    }
  }
}

// ---------------- out = (ctx@Wv^T + bv) @ Wout^T  ----------------
__global__ __launch_bounds__(512) void k_out(const u16* __restrict__ ctx_b,
                                             const u16* __restrict__ Wv_b,
                                             const u16* __restrict__ Wo_b,
                                             const float* __restrict__ taBin,
                                             const float* __restrict__ iaBin,
                                             float* __restrict__ out_t,
                                             float* __restrict__ out_i){
  int gb = blockIdx.x; int b = gb>>1, mha = gb&1;
  int tid = threadIdx.x, lane = tid&63, w = tid>>6;
  const float* bIn = mha? iaBin : taBin;
  const u16* Wv = Wv_b + (size_t)mha*H_*H_;
  const u16* Wo = Wo_b + (size_t)mha*H_*H_;
  const u16* Cp = ctx_b + (size_t)gb*160*H_;
  __shared__ u16 vt[32][784];
  int hd0 = w*HD_;
  {
    f32x4 acc[2][6];
    #pragma unroll
    for(int i=0;i<2;i++)
      #pragma unroll
      for(int j=0;j<6;j++) acc[i][j] = (f32x4){0.f,0.f,0.f,0.f};
    for(int kt=0;kt<24;kt++){
      int ko = kt*32 + (lane>>4)*8;
      bhalf8 a[2];
      #pragma unroll
      for(int mt=0;mt<2;mt++){
        int trow = mt*16 + (lane&15);
        a[mt] = *(const bhalf8*)(Cp + (size_t)(w*T_ + trow)*H_ + ko);
      }
      bhalf8 bb[6];
      #pragma unroll
      for(int j=0;j<6;j++){
        int row = hd0 + j*16 + (lane&15);
        bb[j] = *(const bhalf8*)(Wv + (size_t)row*H_ + ko);
      }
      #pragma unroll
      for(int mt=0;mt<2;mt++)
        #pragma unroll
        for(int j=0;j<6;j++) acc[mt][j] = mfma16(a[mt], bb[j], acc[mt][j]);
    }
    #pragma unroll
    for(int mt=0;mt<2;mt++)
      #pragma unroll
      for(int j=0;j<6;j++){
        int col = j*16 + (lane&15);
        float bv = bIn[2*H_ + hd0 + col];
        #pragma unroll
        for(int rr=0;rr<4;rr++){
          int trow = mt*16 + (lane>>4)*4 + rr;
          vt[trow][hd0 + col] = f2bf(acc[mt][j][rr] + bv);
        }
      }
  }
  __syncthreads();
  {
    f32x4 o[2][6];
    #pragma unroll
    for(int i=0;i<2;i++)
      #pragma unroll
      for(int j=0;j<6;j++) o[i][j] = (f32x4){0.f,0.f,0.f,0.f};
    for(int kt=0;kt<24;kt++){
      int ko = kt*32 + (lane>>4)*8;
      bhalf8 a[2];
      #pragma unroll
      for(int mt=0;mt<2;mt++)
        a[mt] = *(const bhalf8*)(&vt[mt*16 + (lane&15)][ko]);
      bhalf8 bb[6];
      #pragma unroll
      for(int j=0;j<6;j++){
        int row = (w*6+j)*16 + (lane&15);
        bb[j] = *(const bhalf8*)(Wo + (size_t)row*H_ + ko);
      }
      #pragma unroll
      for(int mt=0;mt<2;mt++)
        #pragma unroll
        for(int j=0;j<6;j++) o[mt][j] = mfma16(a[mt], bb[j], o[mt][j]);
    }
    float* op = (mha? out_i : out_t) + (size_t)b*T_*H_;
    #pragma unroll
    for(int mt=0;mt<2;mt++)
      #pragma unroll
      for(int j=0;j<6;j++){
        int col = (w*6+j)*16 + (lane&15);
        #pragma unroll
        for(int rr=0;rr<4;rr++){
          int trow = mt*16 + (lane>>4)*4 + rr;
          if(trow < T_) op[(size_t)trow*H_ + col] = o[mt][j][rr];
        }
      }
  }
}

// ---- cap = relu(LN(comb @ laW^T + laB)), comb blended in-register ----
__global__ __launch_bounds__(512) void k_cap3(const float* __restrict__ out_t,
                                              const float* __restrict__ out_i,
                                              const float* __restrict__ taBout,
                                              const float* __restrict__ iaBout,
                                              const float* __restrict__ rel,
                                              const u16* __restrict__ laW_b,
                                              const float* __restrict__ laB,
                                              const float* __restrict__ laG,
                                              const float* __restrict__ laBe,
                                              float* __restrict__ cap){
  int blk = blockIdx.x; int row0 = blk*16;
  int tid = threadIdx.x, lane = tid&63, w = tid>>6;
  __shared__ float sy[16][776];
  __shared__ float sbo[H_], sbi[H_];
  for(int j=tid;j<H_;j+=512){ sbo[j]=taBout[j]; sbi[j]=iaBout[j]; }
  __syncthreads();
  int arow = row0 + (lane&15);
  float beta = rel[arow/T_];
  f32x4 acc[6];
  #pragma unroll
  for(int j=0;j<6;j++) acc[j] = (f32x4){0.f,0.f,0.f,0.f};
  for(int kt=0;kt<24;kt++){
    int ko = kt*32 + (lane>>4)*8;
    const float* tp = out_t + (size_t)arow*H_ + ko;
    const float* ip = out_i + (size_t)arow*H_ + ko;
    float4 t0 = *(const float4*)tp, t1 = *(const float4*)(tp+4);
    float4 i0 = *(const float4*)ip, i1 = *(const float4*)(ip+4);
    float v[8];
    v[0] = beta*(i0.x+sbi[ko+0]) + (1.f-beta)*(t0.x+sbo[ko+0]);
    v[1] = beta*(i0.y+sbi[ko+1]) + (1.f-beta)*(t0.y+sbo[ko+1]);
    v[2] = beta*(i0.z+sbi[ko+2]) + (1.f-beta)*(t0.z+sbo[ko+2]);
    v[3] = beta*(i0.w+sbi[ko+3]) + (1.f-beta)*(t0.w+sbo[ko+3]);
    v[4] = beta*(i1.x+sbi[ko+4]) + (1.f-beta)*(t1.x+sbo[ko+4]);
    v[5] = beta*(i1.y+sbi[ko+5]) + (1.f-beta)*(t1.y+sbo[ko+5]);
    v[6] = beta*(i1.z+sbi[ko+6]) + (1.f-beta)*(t1.z+sbo[ko+6]);
    v[7] = beta*(i1.w+sbi[ko+7]) + (1.f-beta)*(t1.w+sbo[ko+7]);
    U8 u;
    u.u[0]=cvtpk(v[0],v[1]); u.u[1]=cvtpk(v[2],v[3]);
    u.u[2]=cvtpk(v[4],v[5]); u.u[3]=cvtpk(v[6],v[7]);
    bhalf8 a = u.s;
    bhalf8 bb[6];
    #pragma unroll
    for(int j=0;j<6;j++){
      int row = (w*6+j)*16 + (lane&15);
      bb[j] = *(const bhalf8*)(laW_b + (size_t)row*H_ + ko);
    }
    #pragma unroll
    for(int j=0;j<6;j++) acc[j] = mfma16(a, bb[j], acc[j]);
  }
  #pragma unroll
  for(int j=0;j<6;j++){
    int c = (w*6+j)*16 + (lane&15);
    float lb = laB[c];
    #pragma unroll
    for(int rr=0;rr<4;rr++){
      int r = (lane>>4)*4 + rr;
      sy[r][c] = acc[j][rr] + lb;
    }
  }
  __syncthreads();
  for(int ri=0; ri<2; ri++){
    int r = w*2 + ri;
    float v[12];
    float s = 0.f;
    #pragma unroll
    for(int i=0;i<12;i++){ v[i] = sy[r][lane + 64*i]; s += v[i]; }
    s = wsum(s);
    float mean = s/(float)H_;
    float pv = 0.f;
    #pragma unroll
    for(int i=0;i<12;i++){ float d = v[i]-mean; pv += d*d; }
    pv = wsum(pv);
    float rstd = rsqrtf(pv/(float)H_ + 1e-5f);
    float* cp = cap + (size_t)(row0 + r)*H_;
    #pragma unroll
    for(int i=0;i<12;i++){
      int c = lane + 64*i;
      float o = (v[i]-mean)*rstd*laG[c] + laBe[c];
      cp[c] = (o>0.f)? o : 0.f;
    }
  }
}

// ------- fused quality head -------
__global__ __launch_bounds__(512) void k_quality2(const float* __restrict__ cap,
                                                  const u16* __restrict__ qW1_b,
                                                  const float* __restrict__ qB1,
                                                  const float* __restrict__ qG,
                                                  const float* __restrict__ qBe,
                                                  const float* __restrict__ qW2,
                                                  const float* __restrict__ qB2,
                                                  float* __restrict__ outq){
  const int H2 = H_/2;
  int b0 = blockIdx.x*16;
  int tid = threadIdx.x, lane = tid&63, w = tid>>6;
  __shared__ u16 sm_a[16][772];
  __shared__ float sy[16][388];
  for(int e=tid; e<16*H_; e+=512){
    int r = e/H_, c = e%H_;
    const float* cp = cap + ((size_t)(b0+r)*T_)*H_ + c;
    float s = 0.f;
    #pragma unroll
    for(int t=0;t<T_;t++) s += cp[(size_t)t*H_];
    sm_a[r][c] = f2bf(s*(1.f/(float)T_));
  }
  __syncthreads();
  f32x4 acc[3];
  #pragma unroll
  for(int j=0;j<3;j++) acc[j] = (f32x4){0.f,0.f,0.f,0.f};
  for(int kt=0;kt<24;kt++){
    int ko = kt*32 + (lane>>4)*8;
    bhalf8 a = *(const bhalf8*)(&sm_a[lane&15][ko]);
    bhalf8 bb[3];
    #pragma unroll
    for(int j=0;j<3;j++){
      int row = (w*3+j)*16 + (lane&15);
      bb[j] = *(const bhalf8*)(qW1_b + (size_t)row*H_ + ko);
    }
    #pragma unroll
    for(int j=0;j<3;j++) acc[j] = mfma16(a, bb[j], acc[j]);
  }
  #pragma unroll
  for(int j=0;j<3;j++){
    int c = (w*3+j)*16 + (lane&15);
    float q1 = qB1[c];
    #pragma unroll
    for(int rr=0;rr<4;rr++){
      int r = (lane>>4)*4 + rr;
      sy[r][c] = acc[j][rr] + q1;
    }
  }
  __syncthreads();
  for(int ri=0; ri<2; ri++){
    int r = w*2 + ri;
    float v[6]; float s = 0.f;
    #pragma unroll
    for(int i=0;i<6;i++){ v[i] = sy[r][lane + 64*i]; s += v[i]; }
    s = wsum(s);
    float mean = s/(float)H2;
    float pv = 0.f;
    #pragma unroll
    for(int i=0;i<6;i++){ float d = v[i]-mean; pv += d*d; }
    pv = wsum(pv);
    float rstd = rsqrtf(pv/(float)H2 + 1e-5f);
    float dot = 0.f;
    #pragma unroll
    for(int i=0;i<6;i++){
      int c = lane + 64*i;
      float u = (v[i]-mean)*rstd*qG[c] + qBe[c];
      u = (u>0.f)? u : 0.f;
      dot += u*qW2[c];
    }
    dot = wsum(dot);
    if(lane==0){
      float z = dot + qB2[0];
      outq[b0+r] = 1.f/(1.f+__expf(-z));
    }
  }
}

extern "C" void kernel_launch(void* const* d_in, const int* in_sizes, int n_in,
                              void* d_out, int out_size, void* d_ws, size_t ws_size,
                              hipStream_t stream){
  const float* ehs    = (const float*)d_in[0];
  const float* rel    = (const float*)d_in[1];
  const float* tW1    = (const float*)d_in[3];
  const float* tb1    = (const float*)d_in[4];
  const float* tg     = (const float*)d_in[5];
  const float* tbe    = (const float*)d_in[6];
  const float* tW2    = (const float*)d_in[7];
  const float* tb2    = (const float*)d_in[8];
  const float* iW1    = (const float*)d_in[9];
  const float* ib1    = (const float*)d_in[10];
  const float* ig     = (const float*)d_in[11];
  const float* ibe    = (const float*)d_in[12];
  const float* iW2    = (const float*)d_in[13];
  const float* ib2    = (const float*)d_in[14];
  const float* taWin  = (const float*)d_in[15];
  const float* taBin  = (const float*)d_in[16];
  const float* taWout = (const float*)d_in[17];
  const float* taBout = (const float*)d_in[18];
  const float* iaWin  = (const float*)d_in[19];
  const float* iaBin  = (const float*)d_in[20];
  const float* iaWout = (const float*)d_in[21];
  const float* iaBout = (const float*)d_in[22];
  const float* laW    = (const float*)d_in[23];
  const float* laB    = (const float*)d_in[24];
  const float* laG    = (const float*)d_in[25];
  const float* laBe   = (const float*)d_in[26];
  const float* qW1    = (const float*)d_in[27];
  const float* qB1    = (const float*)d_in[28];
  const float* qG     = (const float*)d_in[29];
  const float* qBe    = (const float*)d_in[30];
  const float* qW2    = (const float*)d_in[31];
  const float* qB2    = (const float*)d_in[32];
  const int* smask    = (const int*)d_in[33];
  const int* imask    = (const int*)d_in[34];

  char* p = (char*)d_ws;
  auto take = [&](size_t bytes)->char*{
    char* r = p; p += (bytes + 255) & ~(size_t)255; return r;
  };
  float* st      = (float*)take((size_t)B_*H_*4);
  float* si      = (float*)take((size_t)B_*H_*4);
  u16*  pt_b     = (u16*)take((size_t)B_*H_*2);
  u16*  pi_b     = (u16*)take((size_t)B_*H_*2);
  u16*  query_b  = (u16*)take((size_t)B_*32*H_*2);
  u16*  WkT      = (u16*)take((size_t)2*H_*H_*2);
  // NOTE: the next 12 matrices are contiguous — k_cvtall relies on it
  u16*  Wq_b     = (u16*)take((size_t)2*H_*H_*2);
  u16*  Wv_b     = (u16*)take((size_t)2*H_*H_*2);
  u16*  Wo_b     = (u16*)take((size_t)2*H_*H_*2);
  u16*  laW_b    = (u16*)take((size_t)H_*H_*2);
  u16*  tW1_b    = (u16*)take((size_t)H_*H_*2);
  u16*  tW2_b    = (u16*)take((size_t)H_*H_*2);
  u16*  iW1_b    = (u16*)take((size_t)H_*H_*2);
  u16*  iW2_b    = (u16*)take((size_t)H_*H_*2);
  u16*  qW1_b    = (u16*)take((size_t)(H_/2)*H_*2);
  float* bias_ws = (float*)take((size_t)B_*2*160*4);
  float* pool_f  = (float*)take((size_t)2*B_*8*H_*4);
  u16*  U_b      = (u16*)take((size_t)B_*2*160*H_*2);   // aliased by ctx_b
  u16*  P_b      = (u16*)take((size_t)B_*2*160*S_*2);
  float* out_t   = (float*)take((size_t)B_*T_*H_*4);
  float* out_i   = (float*)take((size_t)B_*T_*H_*4);
  u16*  ehs_b    = (u16*)take((size_t)B_*S_*H_*2);
  u16*  ehsT     = (u16*)take((size_t)B_*H_*S_*2);
  u16*  ctx_b    = U_b;

  // ehs layout prep + fused masked pool partials
  hipLaunchKernelGGL(k_prep, dim3(B_*96), dim3(256), 0, stream,
                     ehs, smask, imask, ehs_b, ehsT, pool_f);

  // ALL weight conversions in one launch
  const int NP = (H_*H_)/2;
  const int cvtallg = (11*NP + NP/2 + 255)/256;
  hipLaunchKernelGGL(k_cvtall, dim3(cvtallg), dim3(256), 0, stream,
                     taWin, iaWin, taWin + 2*H_*H_, iaWin + 2*H_*H_,
                     taWout, iaWout, laW, tW1, tW2, iW1, iW2, qW1, Wq_b);
  hipLaunchKernelGGL(k_wkt, dim3(1152), dim3(256), 0, stream, taWin, iaWin, WkT);

  // pooling finalize + seeds + query
  hipLaunchKernelGGL(k_poolfin, dim3(B_), dim3(256), 0, stream,
                     pool_f, smask, imask, pt_b, pi_b);
  hipLaunchKernelGGL(k_seed2, dim3(B_/8), dim3(512), 0, stream,
                     pt_b, pi_b, tW1_b, tb1, tg, tbe, tW2_b, tb2,
                     iW1_b, ib1, ig, ibe, iW2_b, ib2, st, si);
  hipLaunchKernelGGL(k_query, dim3(B_), dim3(256), 0, stream, st, si, rel, query_b);

  // attention pipeline
  hipLaunchKernelGGL(k_qu,      dim3(B_*2), dim3(512), 0, stream,
                     query_b, Wq_b, WkT, taBin, iaBin, U_b, bias_ws);
  hipLaunchKernelGGL(k_scores2, dim3(B_*4), dim3(512), 0, stream, ehs_b, U_b, bias_ws, smask, imask, P_b);
  hipLaunchKernelGGL(k_ctx2,    dim3(B_*4), dim3(512), 0, stream, ehsT, P_b, ctx_b);
  hipLaunchKernelGGL(k_out,     dim3(B_*2), dim3(512), 0, stream, ctx_b, Wv_b, Wo_b, taBin, iaBin, out_t, out_i);

  // epilogue
  float* cap = (float*)d_out;
  hipLaunchKernelGGL(k_cap3, dim3((B_*T_)/16), dim3(512), 0, stream,
                     out_t, out_i, taBout, iaBout, rel, laW_b, laB, laG, laBe, cap);
  hipLaunchKernelGGL(k_quality2, dim3(B_/16), dim3(512), 0, stream,
                     cap, qW1_b, qB1, qG, qBe, qW2, qB2, cap + (size_t)B_*T_*H_);
}